// Round 16
// baseline (1220.848 us; speedup 1.0000x reference)
//
#include <hip/hip_runtime.h>

#define NN 100000
#define NE 1600000
#define HD 128
#define EPSV 1e-8f
#define EB 64       // edges per tile (k_edge; 2 tiles per block)
#define LPAD 136    // padded LDS row (bf16 elems): 272 B, 16B-aligned

typedef unsigned short ushort_t;
typedef __attribute__((ext_vector_type(8))) short bf16x8;
typedef __attribute__((ext_vector_type(4))) float f32x4;

__device__ __forceinline__ float silu_f(float x) {
    return x * __builtin_amdgcn_rcpf(1.0f + __expf(-x));
}
__device__ __forceinline__ float b2f(unsigned short u) {
    union { unsigned int i; float f; } v; v.i = ((unsigned int)u) << 16; return v.f;
}
__device__ __forceinline__ unsigned short f2b(float f) {
    union { float f; unsigned int i; } v; v.f = f;
    unsigned int r = v.i + 0x7fff + ((v.i >> 16) & 1);
    return (unsigned short)(r >> 16);
}
__device__ __forceinline__ unsigned int cvt_pk_bf16(float lo, float hi) {
    unsigned int r;
    asm("v_cvt_pk_bf16_f32 %0, %1, %2" : "=v"(r) : "v"(lo), "v"(hi));
    return r;
}
// build a bf16x8 fragment from 8 consecutive fp32 at p (16B-aligned x2)
__device__ __forceinline__ bf16x8 frag_from_f32(const float* p) {
    float4 a0 = *(const float4*)p;
    float4 a1 = *(const float4*)(p + 4);
    union { bf16x8 v; uint4 u; } r;
    r.u.x = cvt_pk_bf16(a0.x, a0.y); r.u.y = cvt_pk_bf16(a0.z, a0.w);
    r.u.z = cvt_pk_bf16(a1.x, a1.y); r.u.w = cvt_pk_bf16(a1.z, a1.w);
    return r.v;
}

// ---------------------------------------------------------------------------
// Kernel 0: fused hist (1.6M edges) + bf16 transposed weight tables.
// ---------------------------------------------------------------------------
extern "C" __global__ __launch_bounds__(256)
void k_prep_hist(const int* __restrict__ ei, int* __restrict__ deg,
                 const float* __restrict__ We2, const float* __restrict__ Wc1,
                 const float* __restrict__ We1, const float* __restrict__ Wn1,
                 const float* __restrict__ Wn2,
                 ushort_t* __restrict__ We2T, ushort_t* __restrict__ Wc1T,
                 ushort_t* __restrict__ WabT, ushort_t* __restrict__ Wn1T,
                 ushort_t* __restrict__ Wn2T)
{
    int id = blockIdx.x * 256 + threadIdx.x;
    atomicAdd(&deg[ei[id]], 1);
    if (id < 16384) {
        int n = id >> 7, k = id & 127;
        We2T[id] = f2b(We2[k * HD + n]);
    } else if (id < 32768) {
        int r = id - 16384; int n = r >> 7, k = r & 127;
        Wc1T[r] = f2b(Wc1[k * HD + n]);
    } else if (id < 65536) {
        int r = id - 32768; int j = r >> 7, k = r & 127;
        float v = (j < 128) ? We1[k * HD + j] : We1[(size_t)(128 + k) * HD + (j - 128)];
        WabT[r] = f2b(v);
    } else if (id < 98304) {
        int r = id - 65536; int j = r >> 8, k = r & 255;
        Wn1T[r] = f2b(Wn1[(size_t)k * HD + j]);
    } else if (id < 114688) {
        int r = id - 98304; int j = r >> 7, k = r & 127;
        Wn2T[r] = f2b(Wn2[k * HD + j]);
    }
}

// ---------------------------------------------------------------------------
// Sort: per-1024-chunk sums -> per-block scan (boff computed inline) -> scatter
// ---------------------------------------------------------------------------
extern "C" __global__ __launch_bounds__(1024)
void k_scan1(const int* __restrict__ deg, int* __restrict__ bsum)
{
    __shared__ int wsum[16];
    const int tid = threadIdx.x;
    const int lane = tid & 63, w = tid >> 6;
    int i = blockIdx.x * 1024 + tid;
    int v = (i < NN) ? deg[i] : 0;
#pragma unroll
    for (int off = 32; off > 0; off >>= 1) v += __shfl_xor(v, off, 64);
    if (lane == 0) wsum[w] = v;
    __syncthreads();
    if (tid == 0) {
        int s = 0;
#pragma unroll
        for (int k = 0; k < 16; k++) s += wsum[k];
        bsum[blockIdx.x] = s;
    }
}

extern "C" __global__ __launch_bounds__(1024)
void k_scan3(const int* __restrict__ deg, const int* __restrict__ bsum,
             int* __restrict__ cursor)
{
    __shared__ int wsum[16];
    __shared__ int boff_s;
    const int tid = threadIdx.x;
    const int lane = tid & 63, w = tid >> 6;
    int i = blockIdx.x * 1024 + tid;
    int v = (i < NN) ? deg[i] : 0;
    int s = v;
#pragma unroll
    for (int off = 1; off < 64; off <<= 1) {
        int t = __shfl_up(s, off, 64);
        if (lane >= off) s += t;
    }
    if (lane == 63) wsum[w] = s;
    if (w == 0) {   // wave 0 also reduces bsum[0..blockIdx-1]
        int a = 0;
        for (int k = lane; k < blockIdx.x; k += 64) a += bsum[k];
#pragma unroll
        for (int off = 32; off > 0; off >>= 1) a += __shfl_xor(a, off, 64);
        if (lane == 0) boff_s = a;
    }
    __syncthreads();
    if (w == 0) {
        int ws = (lane < 16) ? wsum[lane] : 0;
#pragma unroll
        for (int off = 1; off < 16; off <<= 1) {
            int t = __shfl_up(ws, off, 64);
            if (lane >= off) ws += t;
        }
        if (lane < 16) wsum[lane] = ws;
    }
    __syncthreads();
    int excl = boff_s + ((w > 0) ? wsum[w - 1] : 0) + s - v;
    if (i < NN) cursor[i] = excl;
}

extern "C" __global__ __launch_bounds__(256)
void k_sortids(const int* __restrict__ ei, int* __restrict__ cursor,
               int2* __restrict__ rc)
{
    int e = blockIdx.x * 256 + threadIdx.x;
    int r = ei[e], c = ei[NE + e];
    int slot = atomicAdd(&cursor[r], 1);
    rc[slot] = make_int2(r, c);
}

// ---------------------------------------------------------------------------
// Kernel 1: MFMA  [A|B] = bf16(h) @ Wab (+be1 on A half). Operand-swapped.
// No LDS: h fragments are single-use -> loaded directly from global.
// ---------------------------------------------------------------------------
extern "C" __global__ __launch_bounds__(256)
void k_ab(const float* __restrict__ h, const ushort_t* __restrict__ WabT,
          const float* __restrict__ be1,
          ushort_t* __restrict__ A, ushort_t* __restrict__ B)
{
    const int tid = threadIdx.x;
    const int n0 = blockIdx.x * 64;
    const int wave = tid >> 6, lane = tid & 63;
    const int lr = lane & 15, lg = lane >> 4;
    const int node = n0 + wave * 16 + lr;
    const int nsrc = (node < NN) ? node : (NN - 1);

    f32x4 acc[16];
#pragma unroll
    for (int nt = 0; nt < 16; nt++) acc[nt] = (f32x4){0.f, 0.f, 0.f, 0.f};
#pragma unroll
    for (int ks = 0; ks < 4; ks++) {
        bf16x8 hf8 = frag_from_f32(h + (size_t)nsrc * HD + ks * 32 + lg * 8);
#pragma unroll
        for (int nt = 0; nt < 16; nt++) {
            bf16x8 wf = *(const bf16x8*)(WabT + (size_t)(nt * 16 + lr) * HD + ks * 32 + lg * 8);
            acc[nt] = __builtin_amdgcn_mfma_f32_16x16x32_bf16(wf, hf8, acc[nt], 0, 0, 0);
        }
    }
    if (node < NN) {
#pragma unroll
        for (int nt = 0; nt < 16; nt++) {
            float4 bias = (nt < 8) ? ((const float4*)be1)[nt * 4 + lg]
                                   : (float4){0.f, 0.f, 0.f, 0.f};
            uint2 pk;
            pk.x = cvt_pk_bf16(acc[nt][0] + bias.x, acc[nt][1] + bias.y);
            pk.y = cvt_pk_bf16(acc[nt][2] + bias.z, acc[nt][3] + bias.w);
            if (nt < 8)
                *(uint2*)(A + (size_t)node * HD + nt * 16 + lg * 4) = pk;
            else
                *(uint2*)(B + (size_t)node * HD + (nt - 8) * 16 + lg * 4) = pk;
        }
    }
}

// ---------------------------------------------------------------------------
// Kernel 2: MFMA edge kernel — R8 GEMM shape, 2 tiles/block with T14
// register prefetch: tile t+1's rc/coord/B[col] loads issue right after
// tile t's phase-0 consumes them; latency hides under GEMM1+GEMM2.
// No min-waves bound (VGPR headroom to 128 keeps 7 blocks/CU, LDS-limited).
// ---------------------------------------------------------------------------
extern "C" __global__ __launch_bounds__(128)
void k_edge(const int2* __restrict__ rc, const float* __restrict__ coord,
            const ushort_t* __restrict__ A, const ushort_t* __restrict__ B,
            const float* __restrict__ WeL, const float* __restrict__ be2,
            const ushort_t* __restrict__ We2T,
            const ushort_t* __restrict__ Wc1T,
            const float* __restrict__ bc1, const float* __restrict__ Wc2,
            float* __restrict__ agg_h, float* __restrict__ agg_c)
{
    __shared__ ushort_t m_lds[EB][LPAD] __attribute__((aligned(16)));  // 17408
    __shared__ float cd_lds[EB][3];                                    // 768
    __shared__ int rows_s[EB];                                         // 256
    __shared__ float bias_lds[384] __attribute__((aligned(16)));       // be2|bc1|Wc2
    __shared__ float wel_lds[128] __attribute__((aligned(16)));        // 512

    const int tid = threadIdx.x;
    const int e  = tid >> 1;       // edge slot 0..63 (sorted order)
    const int hf = tid & 1;        // feature half
    const int wave = tid >> 6, lane = tid & 63;
    const int lr = lane & 15, lg = lane >> 4;

    // ---- stage biases + WeL into LDS (once) ----
    bias_lds[tid]       = be2[tid];
    bias_lds[128 + tid] = bc1[tid];
    bias_lds[256 + tid] = Wc2[tid];
    wel_lds[tid] = WeL[tid];

    const size_t base = (size_t)blockIdx.x * (2 * EB);

    // ---- prologue: tile 0 edge data into registers ----
    int2 rce = rc[base + e];
    int row = rce.x, col = rce.y;
    float crx = coord[(size_t)row * 3 + 0], cry = coord[(size_t)row * 3 + 1],
          crz = coord[(size_t)row * 3 + 2];
    float ccx = coord[(size_t)col * 3 + 0], ccy = coord[(size_t)col * 3 + 1],
          ccz = coord[(size_t)col * 3 + 2];
    bf16x8 Bst[8];
    {
        const bf16x8* Bp = (const bf16x8*)(B + (size_t)col * HD + hf * 64);
#pragma unroll
        for (int i = 0; i < 8; i++) Bst[i] = Bp[i];
    }

    __syncthreads();   // bias_lds/wel_lds ready

#pragma unroll
    for (int t = 0; t < 2; t++) {
        float c0 = crx - ccx, c1 = cry - ccy, c2 = crz - ccz;
        float radial = c0 * c0 + c1 * c1 + c2 * c2;
        if (hf == 0) {
            rows_s[e] = row;
            float inv = __builtin_amdgcn_rcpf(sqrtf(radial) + EPSV);
            cd_lds[e][0] = c0 * inv; cd_lds[e][1] = c1 * inv; cd_lds[e][2] = c2 * inv;
        }

        // ---- phase 0: m1 = silu(A[row]+Bst+radial*WeL) -> LDS (wave-local) ----
        {
            const bf16x8* A8 = (const bf16x8*)(A + (size_t)row * HD + hf * 64);
            const float4* WL4 = (const float4*)wel_lds + hf * 16;
#pragma unroll
            for (int i = 0; i < 8; i++) {
                bf16x8 av = A8[i], bv = Bst[i];
                float4 w0 = WL4[2 * i], w1 = WL4[2 * i + 1];
                float v0 = silu_f(b2f((ushort_t)av[0]) + b2f((ushort_t)bv[0]) + radial * w0.x);
                float v1 = silu_f(b2f((ushort_t)av[1]) + b2f((ushort_t)bv[1]) + radial * w0.y);
                float v2 = silu_f(b2f((ushort_t)av[2]) + b2f((ushort_t)bv[2]) + radial * w0.z);
                float v3 = silu_f(b2f((ushort_t)av[3]) + b2f((ushort_t)bv[3]) + radial * w0.w);
                float v4 = silu_f(b2f((ushort_t)av[4]) + b2f((ushort_t)bv[4]) + radial * w1.x);
                float v5 = silu_f(b2f((ushort_t)av[5]) + b2f((ushort_t)bv[5]) + radial * w1.y);
                float v6 = silu_f(b2f((ushort_t)av[6]) + b2f((ushort_t)bv[6]) + radial * w1.z);
                float v7 = silu_f(b2f((ushort_t)av[7]) + b2f((ushort_t)bv[7]) + radial * w1.w);
                uint4 p;
                p.x = cvt_pk_bf16(v0, v1); p.y = cvt_pk_bf16(v2, v3);
                p.z = cvt_pk_bf16(v4, v5); p.w = cvt_pk_bf16(v6, v7);
                *(uint4*)&m_lds[e][hf * 64 + i * 8] = p;
            }
        }
        // no barrier: wave w wrote rows [32w,32w+32) and only reads those below

        // ---- prefetch tile 1 (Bst fully consumed above; loads hide under GEMMs) ----
        int nrow = row;
        float ncrx = crx, ncry = cry, ncrz = crz;
        float nccx = ccx, nccy = ccy, nccz = ccz;
        if (t == 0) {
            int2 rcn = rc[base + EB + e];
            nrow = rcn.x;
            int ncol = rcn.y;
            ncrx = coord[(size_t)nrow * 3 + 0]; ncry = coord[(size_t)nrow * 3 + 1];
            ncrz = coord[(size_t)nrow * 3 + 2];
            nccx = coord[(size_t)ncol * 3 + 0]; nccy = coord[(size_t)ncol * 3 + 1];
            nccz = coord[(size_t)ncol * 3 + 2];
            const bf16x8* Bp = (const bf16x8*)(B + (size_t)ncol * HD + hf * 64);
#pragma unroll
            for (int i = 0; i < 8; i++) Bst[i] = Bp[i];
        }

        // ---- GEMM1 (swapped): lane -> m[edge=lr(+16mt)][4 consecutive j] ----
        f32x4 acc[2][8];
#pragma unroll
        for (int mt = 0; mt < 2; mt++)
#pragma unroll
            for (int nt = 0; nt < 8; nt++) acc[mt][nt] = (f32x4){0.f, 0.f, 0.f, 0.f};
#pragma unroll
        for (int ks = 0; ks < 4; ks++) {
            bf16x8 mf0 = *(const bf16x8*)&m_lds[wave * 32 + lr][ks * 32 + lg * 8];
            bf16x8 mf1 = *(const bf16x8*)&m_lds[wave * 32 + 16 + lr][ks * 32 + lg * 8];
#pragma unroll
            for (int nt = 0; nt < 8; nt++) {
                bf16x8 wf = *(const bf16x8*)(We2T + (size_t)(nt * 16 + lr) * HD + ks * 32 + lg * 8);
                acc[0][nt] = __builtin_amdgcn_mfma_f32_16x16x32_bf16(wf, mf0, acc[0][nt], 0, 0, 0);
                acc[1][nt] = __builtin_amdgcn_mfma_f32_16x16x32_bf16(wf, mf1, acc[1][nt], 0, 0, 0);
            }
        }
        // m = silu(acc+be2) -> m_lds[edge][j], b64 packed (wave-local rows)
#pragma unroll
        for (int nt = 0; nt < 8; nt++) {
            float4 be2v = *(const float4*)&bias_lds[nt * 16 + lg * 4];
#pragma unroll
            for (int mt = 0; mt < 2; mt++) {
                float v0 = silu_f(acc[mt][nt][0] + be2v.x);
                float v1 = silu_f(acc[mt][nt][1] + be2v.y);
                float v2 = silu_f(acc[mt][nt][2] + be2v.z);
                float v3 = silu_f(acc[mt][nt][3] + be2v.w);
                uint2 pk; pk.x = cvt_pk_bf16(v0, v1); pk.y = cvt_pk_bf16(v2, v3);
                *(uint2*)&m_lds[wave * 32 + mt * 16 + lr][nt * 16 + lg * 4] = pk;
            }
        }

        // ---- GEMM2 (swapped): m @ Wc1 ----
#pragma unroll
        for (int mt = 0; mt < 2; mt++)
#pragma unroll
            for (int nt = 0; nt < 8; nt++) acc[mt][nt] = (f32x4){0.f, 0.f, 0.f, 0.f};
#pragma unroll
        for (int ks = 0; ks < 4; ks++) {
            bf16x8 mf0 = *(const bf16x8*)&m_lds[wave * 32 + lr][ks * 32 + lg * 8];
            bf16x8 mf1 = *(const bf16x8*)&m_lds[wave * 32 + 16 + lr][ks * 32 + lg * 8];
#pragma unroll
            for (int nt = 0; nt < 8; nt++) {
                bf16x8 wf = *(const bf16x8*)(Wc1T + (size_t)(nt * 16 + lr) * HD + ks * 32 + lg * 8);
                acc[0][nt] = __builtin_amdgcn_mfma_f32_16x16x32_bf16(wf, mf0, acc[0][nt], 0, 0, 0);
                acc[1][nt] = __builtin_amdgcn_mfma_f32_16x16x32_bf16(wf, mf1, acc[1][nt], 0, 0, 0);
            }
        }

        // phi partials over this lane's 4 consecutive j (x2 edges), 2 shuffles
        float ph0 = 0.f, ph1 = 0.f;
#pragma unroll
        for (int nt = 0; nt < 8; nt++) {
            float4 bc1v = *(const float4*)&bias_lds[128 + nt * 16 + lg * 4];
            float4 wc2v = *(const float4*)&bias_lds[256 + nt * 16 + lg * 4];
            ph0 += silu_f(acc[0][nt][0] + bc1v.x) * wc2v.x
                 + silu_f(acc[0][nt][1] + bc1v.y) * wc2v.y
                 + silu_f(acc[0][nt][2] + bc1v.z) * wc2v.z
                 + silu_f(acc[0][nt][3] + bc1v.w) * wc2v.w;
            ph1 += silu_f(acc[1][nt][0] + bc1v.x) * wc2v.x
                 + silu_f(acc[1][nt][1] + bc1v.y) * wc2v.y
                 + silu_f(acc[1][nt][2] + bc1v.z) * wc2v.z
                 + silu_f(acc[1][nt][3] + bc1v.w) * wc2v.w;
        }
        ph0 += __shfl_xor(ph0, 16, 64); ph0 += __shfl_xor(ph0, 32, 64);
        ph1 += __shfl_xor(ph1, 16, 64); ph1 += __shfl_xor(ph1, 32, 64);
        if (lg == 0) {
            int e0 = wave * 32 + lr, e1 = e0 + 16;
            cd_lds[e0][0] *= ph0; cd_lds[e0][1] *= ph0; cd_lds[e0][2] *= ph0;
            cd_lds[e1][0] *= ph1; cd_lds[e1][1] *= ph1; cd_lds[e1][2] *= ph1;
        }

        __syncthreads();   // scatters read all waves' rows

        // ---- agg_h: run-merged scatter (rows sorted); j = tid, es walks 0..63 ----
        {
            const int j = tid;
            float acc_r = 0.f;
            int cur = rows_s[0];
            for (int es = 0; es < EB; es++) {
                int r = rows_s[es];
                if (r != cur) {
                    atomicAdd(&agg_h[(size_t)cur * HD + j], acc_r);
                    acc_r = 0.f; cur = r;
                }
                acc_r += b2f(m_lds[es][j]);
            }
            atomicAdd(&agg_h[(size_t)cur * HD + j], acc_r);
        }
        // ---- agg_c: run-merge, wave 0 only (3 comps x 16 segments of 4) ----
        if (wave == 0) {
            int c = lane >> 4, sub = lane & 15;
            if (c < 3) {
                const int es0 = sub * 4, es1 = es0 + 4;
                float acc_r = 0.f;
                int cur = rows_s[es0];
                for (int es = es0; es < es1; es++) {
                    int r = rows_s[es];
                    if (r != cur) {
                        atomicAdd(&agg_c[(size_t)cur * 3 + c], acc_r);
                        acc_r = 0.f; cur = r;
                    }
                    acc_r += cd_lds[es][c];
                }
                atomicAdd(&agg_c[(size_t)cur * 3 + c], acc_r);
            }
        }

        if (t == 0) {
            row = nrow;
            crx = ncrx; cry = ncry; crz = ncrz;
            ccx = nccx; ccy = nccy; ccz = nccz;
            __syncthreads();   // protect m_lds/cd_lds/rows_s before tile-1 phase-0
        }
    }
}

// ---------------------------------------------------------------------------
// Kernel 3: MFMA node MLP (operand-swapped). GEMM1 fragments loaded directly
// from global (single-use); only u staged in LDS (17.4KB -> 8 blocks/CU).
// ---------------------------------------------------------------------------
extern "C" __global__ __launch_bounds__(256)
void k_node(const float* __restrict__ h, const ushort_t* __restrict__ Wn1T,
            const float* __restrict__ bn1, const ushort_t* __restrict__ Wn2T,
            const float* __restrict__ bn2, const float* __restrict__ coord,
            const int* __restrict__ deg,
            float* __restrict__ hout /* = agg_h in */,
            float* __restrict__ cout /* = agg_c in */)
{
    __shared__ ushort_t us[64][LPAD] __attribute__((aligned(16)));
    const int tid = threadIdx.x;
    const int n0 = blockIdx.x * 64;
    const int wave = tid >> 6, lane = tid & 63;
    const int lr = lane & 15, lg = lane >> 4;
    const int node = n0 + wave * 16 + lr;
    const int nsrc = (node < NN) ? node : (NN - 1);

    // ---- GEMM1 (swapped): cat(h, agg_h)[64,256] @ Wn1 -> u ----
    f32x4 acc[8];
#pragma unroll
    for (int nt = 0; nt < 8; nt++) acc[nt] = (f32x4){0.f, 0.f, 0.f, 0.f};
#pragma unroll
    for (int ks = 0; ks < 8; ks++) {
        const float* src = (ks < 4) ? (h + (size_t)nsrc * HD + ks * 32 + lg * 8)
                                    : (hout + (size_t)nsrc * HD + (ks - 4) * 32 + lg * 8);
        bf16x8 cf = frag_from_f32(src);
#pragma unroll
        for (int nt = 0; nt < 8; nt++) {
            bf16x8 wf = *(const bf16x8*)(Wn1T + (size_t)(nt * 16 + lr) * 256 + ks * 32 + lg * 8);
            acc[nt] = __builtin_amdgcn_mfma_f32_16x16x32_bf16(wf, cf, acc[nt], 0, 0, 0);
        }
    }
#pragma unroll
    for (int nt = 0; nt < 8; nt++) {
        float4 b1 = ((const float4*)bn1)[nt * 4 + lg];
        float v0 = silu_f(acc[nt][0] + b1.x);
        float v1 = silu_f(acc[nt][1] + b1.y);
        float v2 = silu_f(acc[nt][2] + b1.z);
        float v3 = silu_f(acc[nt][3] + b1.w);
        uint2 pk; pk.x = cvt_pk_bf16(v0, v1); pk.y = cvt_pk_bf16(v2, v3);
        *(uint2*)&us[wave * 16 + lr][nt * 16 + lg * 4] = pk;
    }
    // wave-local rows -> no barrier

    // ---- GEMM2 (swapped): u[64,128] @ Wn2 ----
    f32x4 acc2[8];
#pragma unroll
    for (int nt = 0; nt < 8; nt++) acc2[nt] = (f32x4){0.f, 0.f, 0.f, 0.f};
#pragma unroll
    for (int ks = 0; ks < 4; ks++) {
        bf16x8 uf = *(const bf16x8*)&us[wave * 16 + lr][ks * 32 + lg * 8];
#pragma unroll
        for (int nt = 0; nt < 8; nt++) {
            bf16x8 wf = *(const bf16x8*)(Wn2T + (size_t)(nt * 16 + lr) * HD + ks * 32 + lg * 8);
            acc2[nt] = __builtin_amdgcn_mfma_f32_16x16x32_bf16(wf, uf, acc2[nt], 0, 0, 0);
        }
    }
    if (node < NN) {
#pragma unroll
        for (int nt = 0; nt < 8; nt++) {
            float4 b2 = ((const float4*)bn2)[nt * 4 + lg];
            size_t idx = (size_t)node * HD + nt * 16 + lg * 4;
            float4 hv = *(const float4*)(h + idx);
            float4 o;
            o.x = hv.x + acc2[nt][0] + b2.x;
            o.y = hv.y + acc2[nt][1] + b2.y;
            o.z = hv.z + acc2[nt][2] + b2.z;
            o.w = hv.w + acc2[nt][3] + b2.w;
            *(float4*)(hout + idx) = o;
        }
        if (lg == 0) {
            float invc = __builtin_amdgcn_rcpf(fmaxf((float)deg[node], 1.0f));
#pragma unroll
            for (int i = 0; i < 3; i++) {
                size_t idx = (size_t)node * 3 + i;
                cout[idx] = coord[idx] + cout[idx] * invc;
            }
        }
    }
}

// ---------------------------------------------------------------------------
extern "C" void kernel_launch(void* const* d_in, const int* in_sizes, int n_in,
                              void* d_out, int out_size, void* d_ws, size_t ws_size,
                              hipStream_t stream)
{
    const float* h     = (const float*)d_in[0];
    const int*   ei    = (const int*)d_in[1];
    const float* coord = (const float*)d_in[2];
    const float* We1   = (const float*)d_in[3];
    const float* be1   = (const float*)d_in[4];
    const float* We2   = (const float*)d_in[5];
    const float* be2   = (const float*)d_in[6];
    const float* Wn1   = (const float*)d_in[7];
    const float* bn1   = (const float*)d_in[8];
    const float* Wn2   = (const float*)d_in[9];
    const float* bn2   = (const float*)d_in[10];
    const float* Wc1   = (const float*)d_in[11];
    const float* bc1   = (const float*)d_in[12];
    const float* Wc2   = (const float*)d_in[13];

    float* out   = (float*)d_out;
    float* agg_h = out;                         // [NN,128] accum, then h_out
    float* agg_c = out + (size_t)NN * HD;       // [NN,3]  accum, then coord_out

    ushort_t* A    = (ushort_t*)d_ws;            // [NN,128] bf16
    ushort_t* B    = A + (size_t)NN * HD;        // [NN,128] bf16
    ushort_t* We2T = B + (size_t)NN * HD;        // [128,128]
    ushort_t* Wc1T = We2T + 16384;               // [128,128]
    ushort_t* WabT = Wc1T + 16384;               // [256,128]
    ushort_t* Wn1T = WabT + 32768;               // [128,256]
    ushort_t* Wn2T = Wn1T + 32768;               // [128,128]
    int* deg    = (int*)(Wn2T + 16384);          // [NN]
    int* cursor = deg + NN;                      // [NN]
    int* bsum   = cursor + NN;                   // [98]
    int2* rc    = (int2*)(bsum + 128);           // [NE] pre-gathered (row,col)
    const float* WeL = We1 + (size_t)2 * HD * HD;

    const int scan_nb = (NN + 1023) / 1024;      // 98

    hipMemsetAsync(d_out, 0, (size_t)out_size * sizeof(float), stream);
    hipMemsetAsync(deg, 0, (size_t)NN * sizeof(int), stream);

    k_prep_hist<<<NE / 256, 256, 0, stream>>>(ei, deg, We2, Wc1, We1, Wn1, Wn2,
                                              We2T, Wc1T, WabT, Wn1T, Wn2T);
    k_ab<<<(NN + 63) / 64, 256, 0, stream>>>(h, WabT, be1, A, B);
    k_scan1<<<scan_nb, 1024, 0, stream>>>(deg, bsum);
    k_scan3<<<scan_nb, 1024, 0, stream>>>(deg, bsum, cursor);
    k_sortids<<<NE / 256, 256, 0, stream>>>(ei, cursor, rc);
    k_edge<<<NE / (2 * EB), 128, 0, stream>>>(rc, coord, A, B, WeL, be2,
                                              We2T, Wc1T, bc1, Wc2, agg_h, agg_c);
    k_node<<<(NN + 63) / 64, 256, 0, stream>>>(h, Wn1T, bn1, Wn2T, bn2, coord,
                                               deg, agg_h, agg_c);
}

// Round 17
// 873.421 us; speedup vs baseline: 1.3978x; 1.3978x over previous
//
#include <hip/hip_runtime.h>

#define NN 100000
#define NE 1600000
#define HD 128
#define EPSV 1e-8f
#define EB 64       // edges per block (k_edge)
#define LPAD 136    // padded LDS row (bf16 elems): 272 B, 16B-aligned

typedef unsigned short ushort_t;
typedef __attribute__((ext_vector_type(8))) short bf16x8;
typedef __attribute__((ext_vector_type(4))) float f32x4;

__device__ __forceinline__ float silu_f(float x) {
    return x * __builtin_amdgcn_rcpf(1.0f + __expf(-x));
}
__device__ __forceinline__ float b2f(unsigned short u) {
    union { unsigned int i; float f; } v; v.i = ((unsigned int)u) << 16; return v.f;
}
__device__ __forceinline__ unsigned short f2b(float f) {
    union { float f; unsigned int i; } v; v.f = f;
    unsigned int r = v.i + 0x7fff + ((v.i >> 16) & 1);
    return (unsigned short)(r >> 16);
}
__device__ __forceinline__ unsigned int cvt_pk_bf16(float lo, float hi) {
    unsigned int r;
    asm("v_cvt_pk_bf16_f32 %0, %1, %2" : "=v"(r) : "v"(lo), "v"(hi));
    return r;
}
// build a bf16x8 fragment from 8 consecutive fp32 at p (16B-aligned x2)
__device__ __forceinline__ bf16x8 frag_from_f32(const float* p) {
    float4 a0 = *(const float4*)p;
    float4 a1 = *(const float4*)(p + 4);
    union { bf16x8 v; uint4 u; } r;
    r.u.x = cvt_pk_bf16(a0.x, a0.y); r.u.y = cvt_pk_bf16(a0.z, a0.w);
    r.u.z = cvt_pk_bf16(a1.x, a1.y); r.u.w = cvt_pk_bf16(a1.z, a1.w);
    return r.v;
}

// ---------------------------------------------------------------------------
// Kernel 0: fused hist (1.6M edges) + bf16 transposed weight tables.
// ---------------------------------------------------------------------------
extern "C" __global__ __launch_bounds__(256)
void k_prep_hist(const int* __restrict__ ei, int* __restrict__ deg,
                 const float* __restrict__ We2, const float* __restrict__ Wc1,
                 const float* __restrict__ We1, const float* __restrict__ Wn1,
                 const float* __restrict__ Wn2,
                 ushort_t* __restrict__ We2T, ushort_t* __restrict__ Wc1T,
                 ushort_t* __restrict__ WabT, ushort_t* __restrict__ Wn1T,
                 ushort_t* __restrict__ Wn2T)
{
    int id = blockIdx.x * 256 + threadIdx.x;
    atomicAdd(&deg[ei[id]], 1);
    if (id < 16384) {
        int n = id >> 7, k = id & 127;
        We2T[id] = f2b(We2[k * HD + n]);
    } else if (id < 32768) {
        int r = id - 16384; int n = r >> 7, k = r & 127;
        Wc1T[r] = f2b(Wc1[k * HD + n]);
    } else if (id < 65536) {
        int r = id - 32768; int j = r >> 7, k = r & 127;
        float v = (j < 128) ? We1[k * HD + j] : We1[(size_t)(128 + k) * HD + (j - 128)];
        WabT[r] = f2b(v);
    } else if (id < 98304) {
        int r = id - 65536; int j = r >> 8, k = r & 255;
        Wn1T[r] = f2b(Wn1[(size_t)k * HD + j]);
    } else if (id < 114688) {
        int r = id - 98304; int j = r >> 7, k = r & 127;
        Wn2T[r] = f2b(Wn2[k * HD + j]);
    }
}

// ---------------------------------------------------------------------------
// Sort: per-1024-chunk sums -> per-block scan (boff computed inline) -> scatter
// ---------------------------------------------------------------------------
extern "C" __global__ __launch_bounds__(1024)
void k_scan1(const int* __restrict__ deg, int* __restrict__ bsum)
{
    __shared__ int wsum[16];
    const int tid = threadIdx.x;
    const int lane = tid & 63, w = tid >> 6;
    int i = blockIdx.x * 1024 + tid;
    int v = (i < NN) ? deg[i] : 0;
#pragma unroll
    for (int off = 32; off > 0; off >>= 1) v += __shfl_xor(v, off, 64);
    if (lane == 0) wsum[w] = v;
    __syncthreads();
    if (tid == 0) {
        int s = 0;
#pragma unroll
        for (int k = 0; k < 16; k++) s += wsum[k];
        bsum[blockIdx.x] = s;
    }
}

extern "C" __global__ __launch_bounds__(1024)
void k_scan3(const int* __restrict__ deg, const int* __restrict__ bsum,
             int* __restrict__ cursor)
{
    __shared__ int wsum[16];
    __shared__ int boff_s;
    const int tid = threadIdx.x;
    const int lane = tid & 63, w = tid >> 6;
    int i = blockIdx.x * 1024 + tid;
    int v = (i < NN) ? deg[i] : 0;
    int s = v;
#pragma unroll
    for (int off = 1; off < 64; off <<= 1) {
        int t = __shfl_up(s, off, 64);
        if (lane >= off) s += t;
    }
    if (lane == 63) wsum[w] = s;
    if (w == 0) {   // wave 0 also reduces bsum[0..blockIdx-1]
        int a = 0;
        for (int k = lane; k < blockIdx.x; k += 64) a += bsum[k];
#pragma unroll
        for (int off = 32; off > 0; off >>= 1) a += __shfl_xor(a, off, 64);
        if (lane == 0) boff_s = a;
    }
    __syncthreads();
    if (w == 0) {
        int ws = (lane < 16) ? wsum[lane] : 0;
#pragma unroll
        for (int off = 1; off < 16; off <<= 1) {
            int t = __shfl_up(ws, off, 64);
            if (lane >= off) ws += t;
        }
        if (lane < 16) wsum[lane] = ws;
    }
    __syncthreads();
    int excl = boff_s + ((w > 0) ? wsum[w - 1] : 0) + s - v;
    if (i < NN) cursor[i] = excl;
}

extern "C" __global__ __launch_bounds__(256)
void k_sortids(const int* __restrict__ ei, int* __restrict__ cursor,
               int2* __restrict__ rc)
{
    int e = blockIdx.x * 256 + threadIdx.x;
    int r = ei[e], c = ei[NE + e];
    int slot = atomicAdd(&cursor[r], 1);
    rc[slot] = make_int2(r, c);
}

// ---------------------------------------------------------------------------
// Kernel 1: MFMA  [A|B] = bf16(h) @ Wab (+be1 on A half). Operand-swapped.
// No LDS: h fragments are single-use -> loaded directly from global.
// ---------------------------------------------------------------------------
extern "C" __global__ __launch_bounds__(256)
void k_ab(const float* __restrict__ h, const ushort_t* __restrict__ WabT,
          const float* __restrict__ be1,
          ushort_t* __restrict__ A, ushort_t* __restrict__ B)
{
    const int tid = threadIdx.x;
    const int n0 = blockIdx.x * 64;
    const int wave = tid >> 6, lane = tid & 63;
    const int lr = lane & 15, lg = lane >> 4;
    const int node = n0 + wave * 16 + lr;
    const int nsrc = (node < NN) ? node : (NN - 1);

    f32x4 acc[16];
#pragma unroll
    for (int nt = 0; nt < 16; nt++) acc[nt] = (f32x4){0.f, 0.f, 0.f, 0.f};
#pragma unroll
    for (int ks = 0; ks < 4; ks++) {
        bf16x8 hf8 = frag_from_f32(h + (size_t)nsrc * HD + ks * 32 + lg * 8);
#pragma unroll
        for (int nt = 0; nt < 16; nt++) {
            bf16x8 wf = *(const bf16x8*)(WabT + (size_t)(nt * 16 + lr) * HD + ks * 32 + lg * 8);
            acc[nt] = __builtin_amdgcn_mfma_f32_16x16x32_bf16(wf, hf8, acc[nt], 0, 0, 0);
        }
    }
    if (node < NN) {
#pragma unroll
        for (int nt = 0; nt < 16; nt++) {
            float4 bias = (nt < 8) ? ((const float4*)be1)[nt * 4 + lg]
                                   : (float4){0.f, 0.f, 0.f, 0.f};
            uint2 pk;
            pk.x = cvt_pk_bf16(acc[nt][0] + bias.x, acc[nt][1] + bias.y);
            pk.y = cvt_pk_bf16(acc[nt][2] + bias.z, acc[nt][3] + bias.w);
            if (nt < 8)
                *(uint2*)(A + (size_t)node * HD + nt * 16 + lg * 4) = pk;
            else
                *(uint2*)(B + (size_t)node * HD + (nt - 8) * 16 + lg * 4) = pk;
        }
    }
}

// ---------------------------------------------------------------------------
// Kernel 2: MFMA edge kernel — R8 proven optimum: 64 edges / 128 threads /
// 2 waves, acc[2][8] (2 MFMAs per weight fragment), biases+WeL in LDS,
// full-column run-merged scatter, single data barrier. No setprio.
// ---------------------------------------------------------------------------
extern "C" __global__ __launch_bounds__(128, 4)
void k_edge(const int2* __restrict__ rc, const float* __restrict__ coord,
            const ushort_t* __restrict__ A, const ushort_t* __restrict__ B,
            const float* __restrict__ WeL, const float* __restrict__ be2,
            const ushort_t* __restrict__ We2T,
            const ushort_t* __restrict__ Wc1T,
            const float* __restrict__ bc1, const float* __restrict__ Wc2,
            float* __restrict__ agg_h, float* __restrict__ agg_c)
{
    __shared__ ushort_t m_lds[EB][LPAD] __attribute__((aligned(16)));  // 17408
    __shared__ float cd_lds[EB][3];                                    // 768
    __shared__ int rows_s[EB];                                         // 256
    __shared__ float bias_lds[384] __attribute__((aligned(16)));       // be2|bc1|Wc2
    __shared__ float wel_lds[128] __attribute__((aligned(16)));        // 512

    const int tid = threadIdx.x;
    const int e  = tid >> 1;       // edge slot 0..63 (sorted order)
    const int hf = tid & 1;        // feature half
    const int wave = tid >> 6, lane = tid & 63;
    const int lr = lane & 15, lg = lane >> 4;

    // ---- stage biases + WeL into LDS ----
    {
        int i = tid;
        bias_lds[i]       = be2[i];
        bias_lds[128 + i] = bc1[i];
        bias_lds[256 + i] = Wc2[i];
        wel_lds[i] = WeL[i];
    }
    int2 rce = rc[blockIdx.x * EB + e];
    const int row = rce.x, col = rce.y;

    float c0 = coord[(size_t)row * 3 + 0] - coord[(size_t)col * 3 + 0];
    float c1 = coord[(size_t)row * 3 + 1] - coord[(size_t)col * 3 + 1];
    float c2 = coord[(size_t)row * 3 + 2] - coord[(size_t)col * 3 + 2];
    float radial = c0 * c0 + c1 * c1 + c2 * c2;
    if (hf == 0) {
        rows_s[e] = row;
        float inv = __builtin_amdgcn_rcpf(sqrtf(radial) + EPSV);
        cd_lds[e][0] = c0 * inv; cd_lds[e][1] = c1 * inv; cd_lds[e][2] = c2 * inv;
    }
    __syncthreads();   // bias_lds/wel_lds ready

    {
        const bf16x8* A8 = (const bf16x8*)(A + (size_t)row * HD + hf * 64);
        const bf16x8* B8 = (const bf16x8*)(B + (size_t)col * HD + hf * 64);
        const float4* WL4 = (const float4*)wel_lds + hf * 16;
#pragma unroll
        for (int i = 0; i < 8; i++) {
            bf16x8 av = A8[i], bv = B8[i];
            float4 w0 = WL4[2 * i], w1 = WL4[2 * i + 1];
            float v0 = silu_f(b2f((ushort_t)av[0]) + b2f((ushort_t)bv[0]) + radial * w0.x);
            float v1 = silu_f(b2f((ushort_t)av[1]) + b2f((ushort_t)bv[1]) + radial * w0.y);
            float v2 = silu_f(b2f((ushort_t)av[2]) + b2f((ushort_t)bv[2]) + radial * w0.z);
            float v3 = silu_f(b2f((ushort_t)av[3]) + b2f((ushort_t)bv[3]) + radial * w0.w);
            float v4 = silu_f(b2f((ushort_t)av[4]) + b2f((ushort_t)bv[4]) + radial * w1.x);
            float v5 = silu_f(b2f((ushort_t)av[5]) + b2f((ushort_t)bv[5]) + radial * w1.y);
            float v6 = silu_f(b2f((ushort_t)av[6]) + b2f((ushort_t)bv[6]) + radial * w1.z);
            float v7 = silu_f(b2f((ushort_t)av[7]) + b2f((ushort_t)bv[7]) + radial * w1.w);
            uint4 p;
            p.x = cvt_pk_bf16(v0, v1); p.y = cvt_pk_bf16(v2, v3);
            p.z = cvt_pk_bf16(v4, v5); p.w = cvt_pk_bf16(v6, v7);
            *(uint4*)&m_lds[e][hf * 64 + i * 8] = p;
        }
    }
    // no barrier: wave w wrote rows [32w,32w+32) and only reads those below

    // ---- GEMM1 (swapped): lane -> m[edge=lr(+16mt)][4 consecutive j] ----
    f32x4 acc[2][8];
#pragma unroll
    for (int mt = 0; mt < 2; mt++)
#pragma unroll
        for (int nt = 0; nt < 8; nt++) acc[mt][nt] = (f32x4){0.f, 0.f, 0.f, 0.f};
#pragma unroll
    for (int ks = 0; ks < 4; ks++) {
        bf16x8 mf0 = *(const bf16x8*)&m_lds[wave * 32 + lr][ks * 32 + lg * 8];
        bf16x8 mf1 = *(const bf16x8*)&m_lds[wave * 32 + 16 + lr][ks * 32 + lg * 8];
#pragma unroll
        for (int nt = 0; nt < 8; nt++) {
            bf16x8 wf = *(const bf16x8*)(We2T + (size_t)(nt * 16 + lr) * HD + ks * 32 + lg * 8);
            acc[0][nt] = __builtin_amdgcn_mfma_f32_16x16x32_bf16(wf, mf0, acc[0][nt], 0, 0, 0);
            acc[1][nt] = __builtin_amdgcn_mfma_f32_16x16x32_bf16(wf, mf1, acc[1][nt], 0, 0, 0);
        }
    }
    // m = silu(acc+be2) -> m_lds[edge][j], b64 packed (wave-local rows)
#pragma unroll
    for (int nt = 0; nt < 8; nt++) {
        float4 be2v = *(const float4*)&bias_lds[nt * 16 + lg * 4];
#pragma unroll
        for (int mt = 0; mt < 2; mt++) {
            float v0 = silu_f(acc[mt][nt][0] + be2v.x);
            float v1 = silu_f(acc[mt][nt][1] + be2v.y);
            float v2 = silu_f(acc[mt][nt][2] + be2v.z);
            float v3 = silu_f(acc[mt][nt][3] + be2v.w);
            uint2 pk; pk.x = cvt_pk_bf16(v0, v1); pk.y = cvt_pk_bf16(v2, v3);
            *(uint2*)&m_lds[wave * 32 + mt * 16 + lr][nt * 16 + lg * 4] = pk;
        }
    }

    // ---- GEMM2 (swapped): m @ Wc1 ----
#pragma unroll
    for (int mt = 0; mt < 2; mt++)
#pragma unroll
        for (int nt = 0; nt < 8; nt++) acc[mt][nt] = (f32x4){0.f, 0.f, 0.f, 0.f};
#pragma unroll
    for (int ks = 0; ks < 4; ks++) {
        bf16x8 mf0 = *(const bf16x8*)&m_lds[wave * 32 + lr][ks * 32 + lg * 8];
        bf16x8 mf1 = *(const bf16x8*)&m_lds[wave * 32 + 16 + lr][ks * 32 + lg * 8];
#pragma unroll
        for (int nt = 0; nt < 8; nt++) {
            bf16x8 wf = *(const bf16x8*)(Wc1T + (size_t)(nt * 16 + lr) * HD + ks * 32 + lg * 8);
            acc[0][nt] = __builtin_amdgcn_mfma_f32_16x16x32_bf16(wf, mf0, acc[0][nt], 0, 0, 0);
            acc[1][nt] = __builtin_amdgcn_mfma_f32_16x16x32_bf16(wf, mf1, acc[1][nt], 0, 0, 0);
        }
    }

    // phi partials over this lane's 4 consecutive j (x2 edges), 2 shuffles
    float ph0 = 0.f, ph1 = 0.f;
#pragma unroll
    for (int nt = 0; nt < 8; nt++) {
        float4 bc1v = *(const float4*)&bias_lds[128 + nt * 16 + lg * 4];
        float4 wc2v = *(const float4*)&bias_lds[256 + nt * 16 + lg * 4];
        ph0 += silu_f(acc[0][nt][0] + bc1v.x) * wc2v.x
             + silu_f(acc[0][nt][1] + bc1v.y) * wc2v.y
             + silu_f(acc[0][nt][2] + bc1v.z) * wc2v.z
             + silu_f(acc[0][nt][3] + bc1v.w) * wc2v.w;
        ph1 += silu_f(acc[1][nt][0] + bc1v.x) * wc2v.x
             + silu_f(acc[1][nt][1] + bc1v.y) * wc2v.y
             + silu_f(acc[1][nt][2] + bc1v.z) * wc2v.z
             + silu_f(acc[1][nt][3] + bc1v.w) * wc2v.w;
    }
    ph0 += __shfl_xor(ph0, 16, 64); ph0 += __shfl_xor(ph0, 32, 64);
    ph1 += __shfl_xor(ph1, 16, 64); ph1 += __shfl_xor(ph1, 32, 64);
    if (lg == 0) {
        int e0 = wave * 32 + lr, e1 = e0 + 16;
        cd_lds[e0][0] *= ph0; cd_lds[e0][1] *= ph0; cd_lds[e0][2] *= ph0;
        cd_lds[e1][0] *= ph1; cd_lds[e1][1] *= ph1; cd_lds[e1][2] *= ph1;
    }

    __syncthreads();   // scatters read all waves' rows

    // ---- agg_h: run-merged scatter (rows sorted); j = tid, es walks 0..63 ----
    {
        const int j = tid;
        float acc_r = 0.f;
        int cur = rows_s[0];
        for (int es = 0; es < EB; es++) {
            int r = rows_s[es];
            if (r != cur) {
                atomicAdd(&agg_h[(size_t)cur * HD + j], acc_r);
                acc_r = 0.f; cur = r;
            }
            acc_r += b2f(m_lds[es][j]);
        }
        atomicAdd(&agg_h[(size_t)cur * HD + j], acc_r);
    }
    // ---- agg_c: run-merge, wave 0 only (3 comps x 16 segments of 4) ----
    if (wave == 0) {
        int c = lane >> 4, sub = lane & 15;
        if (c < 3) {
            const int es0 = sub * 4, es1 = es0 + 4;
            float acc_r = 0.f;
            int cur = rows_s[es0];
            for (int es = es0; es < es1; es++) {
                int r = rows_s[es];
                if (r != cur) {
                    atomicAdd(&agg_c[(size_t)cur * 3 + c], acc_r);
                    acc_r = 0.f; cur = r;
                }
                acc_r += cd_lds[es][c];
            }
            atomicAdd(&agg_c[(size_t)cur * 3 + c], acc_r);
        }
    }
}

// ---------------------------------------------------------------------------
// Kernel 3: MFMA node MLP (operand-swapped). GEMM1 fragments loaded directly
// from global (single-use); only u staged in LDS (17.4KB -> 8 blocks/CU).
// ---------------------------------------------------------------------------
extern "C" __global__ __launch_bounds__(256)
void k_node(const float* __restrict__ h, const ushort_t* __restrict__ Wn1T,
            const float* __restrict__ bn1, const ushort_t* __restrict__ Wn2T,
            const float* __restrict__ bn2, const float* __restrict__ coord,
            const int* __restrict__ deg,
            float* __restrict__ hout /* = agg_h in */,
            float* __restrict__ cout /* = agg_c in */)
{
    __shared__ ushort_t us[64][LPAD] __attribute__((aligned(16)));
    const int tid = threadIdx.x;
    const int n0 = blockIdx.x * 64;
    const int wave = tid >> 6, lane = tid & 63;
    const int lr = lane & 15, lg = lane >> 4;
    const int node = n0 + wave * 16 + lr;
    const int nsrc = (node < NN) ? node : (NN - 1);

    // ---- GEMM1 (swapped): cat(h, agg_h)[64,256] @ Wn1 -> u ----
    f32x4 acc[8];
#pragma unroll
    for (int nt = 0; nt < 8; nt++) acc[nt] = (f32x4){0.f, 0.f, 0.f, 0.f};
#pragma unroll
    for (int ks = 0; ks < 8; ks++) {
        const float* src = (ks < 4) ? (h + (size_t)nsrc * HD + ks * 32 + lg * 8)
                                    : (hout + (size_t)nsrc * HD + (ks - 4) * 32 + lg * 8);
        bf16x8 cf = frag_from_f32(src);
#pragma unroll
        for (int nt = 0; nt < 8; nt++) {
            bf16x8 wf = *(const bf16x8*)(Wn1T + (size_t)(nt * 16 + lr) * 256 + ks * 32 + lg * 8);
            acc[nt] = __builtin_amdgcn_mfma_f32_16x16x32_bf16(wf, cf, acc[nt], 0, 0, 0);
        }
    }
#pragma unroll
    for (int nt = 0; nt < 8; nt++) {
        float4 b1 = ((const float4*)bn1)[nt * 4 + lg];
        float v0 = silu_f(acc[nt][0] + b1.x);
        float v1 = silu_f(acc[nt][1] + b1.y);
        float v2 = silu_f(acc[nt][2] + b1.z);
        float v3 = silu_f(acc[nt][3] + b1.w);
        uint2 pk; pk.x = cvt_pk_bf16(v0, v1); pk.y = cvt_pk_bf16(v2, v3);
        *(uint2*)&us[wave * 16 + lr][nt * 16 + lg * 4] = pk;
    }
    // wave-local rows -> no barrier

    // ---- GEMM2 (swapped): u[64,128] @ Wn2 ----
    f32x4 acc2[8];
#pragma unroll
    for (int nt = 0; nt < 8; nt++) acc2[nt] = (f32x4){0.f, 0.f, 0.f, 0.f};
#pragma unroll
    for (int ks = 0; ks < 4; ks++) {
        bf16x8 uf = *(const bf16x8*)&us[wave * 16 + lr][ks * 32 + lg * 8];
#pragma unroll
        for (int nt = 0; nt < 8; nt++) {
            bf16x8 wf = *(const bf16x8*)(Wn2T + (size_t)(nt * 16 + lr) * HD + ks * 32 + lg * 8);
            acc2[nt] = __builtin_amdgcn_mfma_f32_16x16x32_bf16(wf, uf, acc2[nt], 0, 0, 0);
        }
    }
    if (node < NN) {
#pragma unroll
        for (int nt = 0; nt < 8; nt++) {
            float4 b2 = ((const float4*)bn2)[nt * 4 + lg];
            size_t idx = (size_t)node * HD + nt * 16 + lg * 4;
            float4 hv = *(const float4*)(h + idx);
            float4 o;
            o.x = hv.x + acc2[nt][0] + b2.x;
            o.y = hv.y + acc2[nt][1] + b2.y;
            o.z = hv.z + acc2[nt][2] + b2.z;
            o.w = hv.w + acc2[nt][3] + b2.w;
            *(float4*)(hout + idx) = o;
        }
        if (lg == 0) {
            float invc = __builtin_amdgcn_rcpf(fmaxf((float)deg[node], 1.0f));
#pragma unroll
            for (int i = 0; i < 3; i++) {
                size_t idx = (size_t)node * 3 + i;
                cout[idx] = coord[idx] + cout[idx] * invc;
            }
        }
    }
}

// ---------------------------------------------------------------------------
extern "C" void kernel_launch(void* const* d_in, const int* in_sizes, int n_in,
                              void* d_out, int out_size, void* d_ws, size_t ws_size,
                              hipStream_t stream)
{
    const float* h     = (const float*)d_in[0];
    const int*   ei    = (const int*)d_in[1];
    const float* coord = (const float*)d_in[2];
    const float* We1   = (const float*)d_in[3];
    const float* be1   = (const float*)d_in[4];
    const float* We2   = (const float*)d_in[5];
    const float* be2   = (const float*)d_in[6];
    const float* Wn1   = (const float*)d_in[7];
    const float* bn1   = (const float*)d_in[8];
    const float* Wn2   = (const float*)d_in[9];
    const float* bn2   = (const float*)d_in[10];
    const float* Wc1   = (const float*)d_in[11];
    const float* bc1   = (const float*)d_in[12];
    const float* Wc2   = (const float*)d_in[13];

    float* out   = (float*)d_out;
    float* agg_h = out;                         // [NN,128] accum, then h_out
    float* agg_c = out + (size_t)NN * HD;       // [NN,3]  accum, then coord_out

    ushort_t* A    = (ushort_t*)d_ws;            // [NN,128] bf16
    ushort_t* B    = A + (size_t)NN * HD;        // [NN,128] bf16
    ushort_t* We2T = B + (size_t)NN * HD;        // [128,128]
    ushort_t* Wc1T = We2T + 16384;               // [128,128]
    ushort_t* WabT = Wc1T + 16384;               // [256,128]
    ushort_t* Wn1T = WabT + 32768;               // [128,256]
    ushort_t* Wn2T = Wn1T + 32768;               // [128,128]
    int* deg    = (int*)(Wn2T + 16384);          // [NN]
    int* cursor = deg + NN;                      // [NN]
    int* bsum   = cursor + NN;                   // [98]
    int2* rc    = (int2*)(bsum + 128);           // [NE] pre-gathered (row,col)
    const float* WeL = We1 + (size_t)2 * HD * HD;

    const int scan_nb = (NN + 1023) / 1024;      // 98

    hipMemsetAsync(d_out, 0, (size_t)out_size * sizeof(float), stream);
    hipMemsetAsync(deg, 0, (size_t)NN * sizeof(int), stream);

    k_prep_hist<<<NE / 256, 256, 0, stream>>>(ei, deg, We2, Wc1, We1, Wn1, Wn2,
                                              We2T, Wc1T, WabT, Wn1T, Wn2T);
    k_ab<<<(NN + 63) / 64, 256, 0, stream>>>(h, WabT, be1, A, B);
    k_scan1<<<scan_nb, 1024, 0, stream>>>(deg, bsum);
    k_scan3<<<scan_nb, 1024, 0, stream>>>(deg, bsum, cursor);
    k_sortids<<<NE / 256, 256, 0, stream>>>(ei, cursor, rc);
    k_edge<<<NE / EB, 128, 0, stream>>>(rc, coord, A, B, WeL, be2,
                                        We2T, Wc1T, bc1, Wc2, agg_h, agg_c);
    k_node<<<(NN + 63) / 64, 256, 0, stream>>>(h, Wn1T, bn1, Wn2T, bn2, coord,
                                               deg, agg_h, agg_c);
}